// Round 1
// 520.854 us; speedup vs baseline: 1.0331x; 1.0331x over previous
//
#include <hip/hip_runtime.h>
#include <stdint.h>

#define Bn 2048
#define Tn 512
#define An 32
#define Hn 16

typedef __attribute__((ext_vector_type(8))) short bf16x8;
typedef __attribute__((ext_vector_type(4))) float f32x4;

union FragU { bf16x8 v; uint32_t u[4]; };

static __device__ __forceinline__ uint32_t pack_hi16(float a, float b){
  return (__float_as_uint(b) & 0xFFFF0000u) | (__float_as_uint(a) >> 16);
}
// split 8 fp32 into hi/lo bf16 fragments (element e = k index e; even k low half of dword)
static __device__ __forceinline__ void split8(const float* s, FragU& hi, FragU& lo){
#pragma unroll
  for (int d = 0; d < 4; ++d){
    float a = s[2*d], b = s[2*d+1];
    float ah = __uint_as_float(__float_as_uint(a) & 0xFFFF0000u);
    float bh = __uint_as_float(__float_as_uint(b) & 0xFFFF0000u);
    hi.u[d] = pack_hi16(a, b);
    lo.u[d] = pack_hi16(a - ah, b - bh);
  }
}
static __device__ __forceinline__ uint32_t plo(uint32_t e, uint32_t o){
  return __builtin_amdgcn_perm(o, e, 0x05040100u);
}
static __device__ __forceinline__ uint32_t phi(uint32_t e, uint32_t o){
  return __builtin_amdgcn_perm(o, e, 0x07060302u);
}
static __device__ __forceinline__ f32x4 MF(const FragU& a, const FragU& b, f32x4 c){
  return __builtin_amdgcn_mfma_f32_16x16x32_bf16(a.v, b.v, c, 0, 0, 0);
}
static __device__ __forceinline__ void packH(const float* hs, uint32_t* pk){
#pragma unroll
  for (int r = 0; r < 4; ++r){
    float hh_ = __uint_as_float(__float_as_uint(hs[r]) & 0xFFFF0000u);
    pk[r] = (__float_as_uint(hs[r] - hh_) & 0xFFFF0000u) | (__float_as_uint(hs[r]) >> 16);
  }
}
// rebuild B-fragments (Hh dup, Hl dup) from packed state via wave-wide bpermute
static __device__ __forceinline__ void buildBH(const uint32_t* pk, int srcA, int srcB,
                                               FragU& BHh, FragU& BHl){
  uint32_t d0 = (uint32_t)__builtin_amdgcn_ds_bpermute(srcA, (int)pk[0]);
  uint32_t d1 = (uint32_t)__builtin_amdgcn_ds_bpermute(srcA, (int)pk[1]);
  uint32_t d2 = (uint32_t)__builtin_amdgcn_ds_bpermute(srcA, (int)pk[2]);
  uint32_t d3 = (uint32_t)__builtin_amdgcn_ds_bpermute(srcA, (int)pk[3]);
  uint32_t d4 = (uint32_t)__builtin_amdgcn_ds_bpermute(srcB, (int)pk[0]);
  uint32_t d5 = (uint32_t)__builtin_amdgcn_ds_bpermute(srcB, (int)pk[1]);
  uint32_t d6 = (uint32_t)__builtin_amdgcn_ds_bpermute(srcB, (int)pk[2]);
  uint32_t d7 = (uint32_t)__builtin_amdgcn_ds_bpermute(srcB, (int)pk[3]);
  BHh.u[0] = plo(d0, d1); BHh.u[1] = plo(d2, d3);
  BHh.u[2] = plo(d4, d5); BHh.u[3] = plo(d6, d7);
  BHl.u[0] = phi(d0, d1); BHl.u[1] = phi(d2, d3);
  BHl.u[2] = phi(d4, d5); BHl.u[3] = phi(d6, d7);
}

// Single-wave-per-tile LSTM: one 64-lane wave owns all 4 gates for a 16-batch tile.
// No barriers, no LDS in the recurrent loop. Activation scaling (-log2e / 2log2e)
// is pre-folded into the weights/biases so act = rcp(1+exp2(gate)).
__global__ __launch_bounds__(64, 1)
void lstm_fused(const float* __restrict__ xin,   // [B,T,32]
                const float* __restrict__ masks, // [B,T]
                const float* __restrict__ h0,    // [B,16]
                const float* __restrict__ c0,    // [B,16]
                const float* __restrict__ w_ih,  // [64,32]
                const float* __restrict__ w_hh,  // [64,16]
                const float* __restrict__ b_ih,  // [64]
                const float* __restrict__ b_hh,  // [64]
                const float* __restrict__ w_act, // [32,16]
                const float* __restrict__ b_act, // [32]
                const float* __restrict__ w_cr,  // [16]
                const float* __restrict__ b_cr,  // [1]
                float* __restrict__ actor,       // [B,T,32]
                float* __restrict__ critic,      // [B,T]
                float* __restrict__ hT,          // [B,16]
                float* __restrict__ cT)          // [B,16]
{
  const int l = threadIdx.x;           // 0..63
  const int q = l >> 4;
  const int n = l & 15;
  const int b0 = blockIdx.x * 16;
  const int colbase = (q & 1) * 8;
  const bool hiQuad = (q < 2);

  const float KS = -1.44269504088896f; // sigmoid gates: sigm(x)=rcp(1+exp2(KS*x))
  const float KG =  2.88539008177793f; // tanh gate:     tanh(x)=1-2*rcp(1+exp2(KG*x))

  // ---- per-gate weight fragments (all 4 gates in this wave), pre-scaled ----
  FragU wihH0, wihL0, whh10, whh20; f32x4 bias0;
  FragU wihH1, wihL1, whh11, whh21; f32x4 bias1;
  FragU wihH2, wihL2, whh12, whh22; f32x4 bias2;
  FragU wihH3, wihL3, whh13, whh23; f32x4 bias3;
  {
    auto loadGate = [&](int g, float sc, FragU& wh, FragU& wl, FragU& a1, FragU& a2, f32x4& bg){
      float tmp[8];
#pragma unroll
      for (int j = 0; j < 8; ++j) tmp[j] = w_ih[(g*16 + n)*32 + q*8 + j] * sc;
      split8(tmp, wh, wl);
#pragma unroll
      for (int j = 0; j < 8; ++j) tmp[j] = w_hh[(g*16 + n)*16 + colbase + j] * sc;
      FragU hh, hl; split8(tmp, hh, hl);
#pragma unroll
      for (int d = 0; d < 4; ++d){
        a1.u[d] = hiQuad ? hh.u[d] : hl.u[d];  // [Whh_hi | Whh_lo]
        a2.u[d] = hiQuad ? hh.u[d] : 0u;       // [Whh_hi | 0]
      }
#pragma unroll
      for (int r = 0; r < 4; ++r)
        bg[r] = (b_ih[g*16 + q*4 + r] + b_hh[g*16 + q*4 + r]) * sc;
    };
    loadGate(0, KS, wihH0, wihL0, whh10, whh20, bias0);  // i
    loadGate(1, KS, wihH1, wihL1, whh11, whh21, bias1);  // f
    loadGate(2, KG, wihH2, wihL2, whh12, whh22, bias2);  // g (tanh)
    loadGate(3, KS, wihH3, wihL3, whh13, whh23, bias3);  // o
  }

  // ---- head weights (actor 2 tiles + critic), unscaled ----
  FragU whA10, whA20, whA11, whA21, wcA1, wcA2;
  f32x4 biasA0, biasA1;
  const float bcr = b_cr[0];
  {
    float tmp[8];
#pragma unroll
    for (int j = 0; j < 8; ++j) tmp[j] = w_act[(0*16 + n)*16 + colbase + j];
    { FragU hh, hl; split8(tmp, hh, hl);
#pragma unroll
      for (int d = 0; d < 4; ++d){ whA10.u[d] = hiQuad ? hh.u[d] : hl.u[d]; whA20.u[d] = hiQuad ? hh.u[d] : 0u; } }
#pragma unroll
    for (int r = 0; r < 4; ++r) biasA0[r] = b_act[0*16 + q*4 + r];
#pragma unroll
    for (int j = 0; j < 8; ++j) tmp[j] = w_act[(1*16 + n)*16 + colbase + j];
    { FragU hh, hl; split8(tmp, hh, hl);
#pragma unroll
      for (int d = 0; d < 4; ++d){ whA11.u[d] = hiQuad ? hh.u[d] : hl.u[d]; whA21.u[d] = hiQuad ? hh.u[d] : 0u; } }
#pragma unroll
    for (int r = 0; r < 4; ++r) biasA1[r] = b_act[1*16 + q*4 + r];
#pragma unroll
    for (int j = 0; j < 8; ++j) tmp[j] = (n == 0) ? w_cr[colbase + j] : 0.0f;
    { FragU hh, hl; split8(tmp, hh, hl);
#pragma unroll
      for (int d = 0; d < 4; ++d){ wcA1.u[d] = hiQuad ? hh.u[d] : hl.u[d]; wcA2.u[d] = hiQuad ? hh.u[d] : 0u; } }
  }

  const int srcA = (((q & 1) * 2) * 16 + n) * 4;
  const int srcB = srcA + 64;

  // ---- initial state (lane-local: rows q*4+r, batch n) ----
  float cs[4], hs[4];
#pragma unroll
  for (int r = 0; r < 4; ++r){
    hs[r] = h0[(b0 + n)*16 + q*4 + r];
    cs[r] = c0[(b0 + n)*16 + q*4 + r];
  }
  uint32_t pk[4];
  packH(hs, pk);
  FragU BHh, BHl;
  buildBH(pk, srcA, srcB, BHh, BHl);

  const f32x4 zero4 = {0.f, 0.f, 0.f, 0.f};

  // ---- x prefetch: depth-4 rotating register queue ----
  const size_t xrow = (size_t)(b0 + n) * Tn * 32 + q * 8;
  float4 xA[4], xB[4];
#pragma unroll
  for (int u = 0; u < 4; ++u){
    xA[u] = *(const float4*)&xin[xrow + (size_t)u * 32];
    xB[u] = *(const float4*)&xin[xrow + (size_t)u * 32 + 4];
  }
  // masks: direct global prefetch one step ahead (L1-resident lines, reused 16 steps)
  const size_t mrow = (size_t)(b0 + n) * Tn;
  float mCur = masks[mrow];

  for (int t0 = 0; t0 < Tn; t0 += 4){
#pragma unroll
    for (int u = 0; u < 4; ++u){
      const int t = t0 + u;
      const float m = mCur;
      {
        const int tm = (t + 1 < Tn) ? (t + 1) : t;
        mCur = masks[mrow + tm];               // issue early, used next step
      }
      float cm[4];                             // c*m off the post-activation chain
#pragma unroll
      for (int r = 0; r < 4; ++r) cm[r] = cs[r] * m;

      // x fragment (shared by all 4 gates)
      FragU Xh, Xl;
      {
        float s[8] = {xA[u].x, xA[u].y, xA[u].z, xA[u].w,
                      xB[u].x, xB[u].y, xB[u].z, xB[u].w};
        split8(s, Xh, Xl);
      }
      {
        const int tn = (t + 4 < Tn) ? (t + 4) : t;
        xA[u] = *(const float4*)&xin[xrow + (size_t)tn * 32];
        xB[u] = *(const float4*)&xin[xrow + (size_t)tn * 32 + 4];
      }

      // x-part MFMAs (12): issue first — cover bpermute latency from prev step
      f32x4 ax0 = MF(wihH0, Xh, bias0); ax0 = MF(wihH0, Xl, ax0); ax0 = MF(wihL0, Xh, ax0);
      f32x4 ax1 = MF(wihH1, Xh, bias1); ax1 = MF(wihH1, Xl, ax1); ax1 = MF(wihL1, Xh, ax1);
      f32x4 ax2 = MF(wihH2, Xh, bias2); ax2 = MF(wihH2, Xl, ax2); ax2 = MF(wihL2, Xh, ax2);
      f32x4 ax3 = MF(wihH3, Xh, bias3); ax3 = MF(wihH3, Xl, ax3); ax3 = MF(wihL3, Xh, ax3);

      // h-part MFMAs (8): the recurrent dependency
      f32x4 ah0 = MF(whh10, BHh, zero4); ah0 = MF(whh20, BHl, ah0);
      f32x4 ah1 = MF(whh11, BHh, zero4); ah1 = MF(whh21, BHl, ah1);
      f32x4 ah2 = MF(whh12, BHh, zero4); ah2 = MF(whh22, BHl, ah2);
      f32x4 ah3 = MF(whh13, BHh, zero4); ah3 = MF(whh23, BHl, ah3);

      // heads for step t-1 (BH still holds h_{t-1}); issue covers ah latency
      if (t){
        const int th = t - 1;
        f32x4 a0 = MF(whA10, BHh, biasA0); a0 = MF(whA20, BHl, a0);
        *(f32x4*)&actor[((size_t)(b0 + n) * Tn + th) * 32 + 0*16 + q*4] = a0;
        f32x4 a1 = MF(whA11, BHh, biasA1); a1 = MF(whA21, BHl, a1);
        *(f32x4*)&actor[((size_t)(b0 + n) * Tn + th) * 32 + 1*16 + q*4] = a1;
        f32x4 cc = MF(wcA1, BHh, zero4); cc = MF(wcA2, BHl, cc);
        if (q == 0) critic[(size_t)(b0 + n) * Tn + th] = cc[0] + bcr;
      }

      // all-gates activation + state update, fully lane-local (no exchange)
#pragma unroll
      for (int r = 0; r < 4; ++r){
        float gi = ax0[r] + m * ah0[r];
        float gf = ax1[r] + m * ah1[r];
        float gg = ax2[r] + m * ah2[r];
        float go = ax3[r] + m * ah3[r];
        float iv = __builtin_amdgcn_rcpf(1.0f + __builtin_amdgcn_exp2f(gi));
        float fv = __builtin_amdgcn_rcpf(1.0f + __builtin_amdgcn_exp2f(gf));
        float gr = __builtin_amdgcn_rcpf(1.0f + __builtin_amdgcn_exp2f(gg));
        float ov = __builtin_amdgcn_rcpf(1.0f + __builtin_amdgcn_exp2f(go));
        float gv = 1.0f - 2.0f * gr;           // tanh(g)
        float c2 = fv * cm[r] + iv * gv;
        float r2 = __builtin_amdgcn_rcpf(1.0f + __builtin_amdgcn_exp2f(c2 * KG));
        float orr = ov * r2;
        float h2 = ov - 2.0f * orr;            // ov * tanh(c2)
        cs[r] = c2;
        hs[r] = h2;
      }
      packH(hs, pk);
      buildBH(pk, srcA, srcB, BHh, BHl);       // latency covered by next step's x block
    }
  }

  // epilogue: heads for t = Tn-1
  {
    const int th = Tn - 1;
    f32x4 a0 = MF(whA10, BHh, biasA0); a0 = MF(whA20, BHl, a0);
    *(f32x4*)&actor[((size_t)(b0 + n) * Tn + th) * 32 + 0*16 + q*4] = a0;
    f32x4 a1 = MF(whA11, BHh, biasA1); a1 = MF(whA21, BHl, a1);
    *(f32x4*)&actor[((size_t)(b0 + n) * Tn + th) * 32 + 1*16 + q*4] = a1;
    f32x4 cc = MF(wcA1, BHh, zero4); cc = MF(wcA2, BHl, cc);
    if (q == 0) critic[(size_t)(b0 + n) * Tn + th] = cc[0] + bcr;
  }
  *(float4*)&hT[(b0 + n)*16 + q*4] = make_float4(hs[0], hs[1], hs[2], hs[3]);
  *(float4*)&cT[(b0 + n)*16 + q*4] = make_float4(cs[0], cs[1], cs[2], cs[3]);
}

extern "C" void kernel_launch(void* const* d_in, const int* in_sizes, int n_in,
                              void* d_out, int out_size, void* d_ws, size_t ws_size,
                              hipStream_t stream) {
  (void)in_sizes; (void)n_in; (void)out_size; (void)d_ws; (void)ws_size;
  const float* xin   = (const float*)d_in[0];
  const float* masks = (const float*)d_in[1];
  const float* h0    = (const float*)d_in[2];
  const float* c0    = (const float*)d_in[3];
  const float* w_ih  = (const float*)d_in[4];
  const float* w_hh  = (const float*)d_in[5];
  const float* b_ih  = (const float*)d_in[6];
  const float* b_hh  = (const float*)d_in[7];
  const float* w_act = (const float*)d_in[8];
  const float* b_act = (const float*)d_in[9];
  const float* w_cr  = (const float*)d_in[10];
  const float* b_cr  = (const float*)d_in[11];

  float* out    = (float*)d_out;
  float* actor  = out;                                   // [B,T,32]
  float* critic = out + (size_t)Bn * Tn * An;            // [B,T]
  float* hT     = critic + (size_t)Bn * Tn;              // [B,16]
  float* cT     = hT + (size_t)Bn * Hn;                  // [B,16]

  lstm_fused<<<Bn/16, 64, 0, stream>>>(xin, masks, h0, c0, w_ih, w_hh, b_ih, b_hh,
                                       w_act, b_act, w_cr, b_cr,
                                       actor, critic, hT, cT);
}